// Round 1
// 143.970 us; speedup vs baseline: 1.0018x; 1.0018x over previous
//
#include <hip/hip_runtime.h>

// Bilateral 5x5, 3 chained passes FUSED into one kernel.
// [32,1,512,512] fp32, replicate padding, w = exp2(dr^2*nax + dc^2*nay + d^2*ncr).
//
// Round-9: LDS-issue-bound theory. Round-8 (80 us) read a 3-row x 3-quad
// window (9 ds_read_b128) per 4-px unit = 2.25 reads/px; with one LDS pipe
// vs 4 VALU pipes per CU that oversubscribes LDS ~1.6x at full VALU issue
// (VALUBusy 68% = waves parked on lgkmcnt). This round keeps the validated
// packed tap core EXACTLY and switches to 2-row units: 8 px per unit, 4-row
// x 3-quad window (12 reads) = 1.5 reads/px (-33% LDS traffic), half the
// loop/div/addr overhead. Plain __launch_bounds__(256) -- round-7's spills
// came from the (256,5) VGPR cap, not the 2-row structure.
//
// Geometry (every pass reads 16B-aligned LDS quads, center at (r+2, 4q+4)):
//   buf0 staged input : rows [Y0-6,Y0+37] x cols [X0-12,X0+79]  44 x 92
//   buf1 = pass1 out  : rows [Y0-4,Y0+35] x cols [X0- 8,X0+75]  40 x 84
//   buf2 = pass2 out  : rows [Y0-2,Y0+33] x cols [X0- 4,X0+71]  36 x 76 (aliases buf0)
// Staging clamps global coords (buf0 replicate-padded exactly); after
// pass1/pass2 replicate_fill() restores replicate padding of intermediates
// in border blocks (the reference pads each intermediate image).
//
// Pruning (round 3): taps with spatial log2-weight < TH2 skipped via
// block-uniform branches -> effective 3x3 for sigma=0.5 (8 exps/px).
// Generic 5x5 path kept for large sigma.

typedef float v2f __attribute__((ext_vector_type(2)));

#define EXP2(x) __builtin_amdgcn_exp2f(x)
#define RCP(x)  __builtin_amdgcn_rcpf(x)
#define TH2 (-10.0f)

#define TILE_X 64
#define TILE_Y 32
#define S0R 44
#define S0C 92            // 368 B row stride (16B-aligned)
#define S1R 40
#define S1C 84            // 336 B
#define S2R 36
#define S2C 76            // 304 B

// Copy replicate-padding into phantom slots of an LDS image.
// Valid region [rlo,rhi]x[vlo,vhi]; reads valid slots, writes phantom slots
// -> race-free without an internal barrier. Block-uniform early-out.
template<int NR, int NC>
__device__ __forceinline__ void replicate_fill(float* buf, int rlo, int rhi,
                                               int vlo, int vhi, int tid)
{
    if (rlo == 0 && vlo == 0 && rhi == NR - 1 && vhi == NC - 1) return;
    for (int t = tid; t < NR * NC; t += 256) {
        const int r = t / NC, v = t - r * NC;
        const int rs = min(max(r, rlo), rhi);
        const int vs = min(max(v, vlo), vhi);
        if (rs != r || vs != v) buf[r * NC + v] = buf[rs * NC + vs];
    }
}

// Build 6-wide window row (cols c-1 .. c+4) from 3 aligned b128 quads.
__device__ __forceinline__ void mkrow6(const float* p, float* w6)
{
    const float4 L = *(const float4*)(p - 4);
    const float4 M = *(const float4*)(p);
    const float4 R = *(const float4*)(p + 4);
    w6[0] = L.w; w6[1] = M.x; w6[2] = M.y; w6[3] = M.z; w6[4] = M.w;
    w6[5] = R.x;
}

// One packed tap-pair: 5 pk ops + 2 exp for 2 pixels.
__device__ __forceinline__ void tap_pair(v2f nb, v2f ce, v2f& nu, v2f& de,
                                         float b, v2f ncr2)
{
    v2f d  = nb - ce;                                   // pk_add
    v2f tt = __builtin_elementwise_fma(d * d, ncr2,
                                       (v2f){b, b});    // pk_mul+pk_fma
    v2f w  = {EXP2(tt.x), EXP2(tt.y)};
    nu = __builtin_elementwise_fma(w, nb, nu);          // pk_fma
    de += w;                                            // pk_add
}

// All horizontal taps of one window row against centers c01/c23.
__device__ __forceinline__ void row_taps(const float* w6, v2f c01, v2f c23,
                                         v2f& n01, v2f& n23, v2f& d01, v2f& d23,
                                         float bm, float b0, float bp,
                                         bool skip0, v2f ncr2)
{
    tap_pair((v2f){w6[0], w6[1]}, c01, n01, d01, bm, ncr2);   // dc=-1
    tap_pair((v2f){w6[2], w6[3]}, c23, n23, d23, bm, ncr2);
    if (!skip0) {
        tap_pair((v2f){w6[1], w6[2]}, c01, n01, d01, b0, ncr2); // dc=0
        tap_pair((v2f){w6[3], w6[4]}, c23, n23, d23, b0, ncr2);
    }
    tap_pair((v2f){w6[2], w6[3]}, c01, n01, d01, bp, ncr2);   // dc=+1
    tap_pair((v2f){w6[4], w6[5]}, c23, n23, d23, bp, ncr2);
}

// Packed 3x3 bilateral core for 4 px: 16 tap-pairs = 80 pk ops + 32 exp.
__device__ __forceinline__ float4 core3x3(const float* wm, const float* wc,
                                          const float* wp,
                                          float nax, float nay, v2f ncr2)
{
    v2f c01 = {wc[1], wc[2]}, c23 = {wc[3], wc[4]};
    v2f n01 = c01, n23 = c23;               // center tap, w == 1
    v2f d01 = {1.f, 1.f}, d23 = {1.f, 1.f};
    const float bd = nax + nay;
    row_taps(wc, c01, c23, n01, n23, d01, d23, nay, 0.0f, nay, true,  ncr2);
    row_taps(wm, c01, c23, n01, n23, d01, d23, bd,  nax,  bd,  false, ncr2);
    row_taps(wp, c01, c23, n01, n23, d01, d23, bd,  nax,  bd,  false, ncr2);
    float4 o;
    o.x = n01.x * RCP(d01.x);
    o.y = n01.y * RCP(d01.y);
    o.z = n23.x * RCP(d23.x);
    o.w = n23.y * RCP(d23.y);
    return o;
}

// One bilateral pass over a tile held in LDS, 2-row units.
// Unit t -> (row-pair rp, quad q); output rows r0=2rp, r0+1; center quads at
// src[(r0+2)*SST + 4q+4] and src[(r0+3)*SST + 4q+4]; window = 4 rows x 3 quads.
template<int NQ, int NRH, int SST, int DSTST, bool TOG>
__device__ __forceinline__ void bilat_tile_pass(
    const float* __restrict__ src, float* __restrict__ dst,
    float* __restrict__ gout, int W,
    int tid, float ncr, float nax, float nay, bool prune)
{
    const v2f ncr2 = {ncr, ncr};
    for (int t = tid; t < NQ * NRH; t += 256) {
        const int rp = t / NQ;
        const int q  = t - rp * NQ;
        const int r0 = 2 * rp;
        const float* cp = src + (r0 + 2) * SST + 4 * q + 4;   // center row A

        if (prune) {
            // 12 ds_read_b128 for an 8-px unit (1.5 reads/px).
            float w0[6], w1[6], w2[6], w3[6];
            mkrow6(cp - SST,     w0);    // row r0+1 (above A)
            mkrow6(cp,           w1);    // row r0+2 (center A)
            mkrow6(cp + SST,     w2);    // row r0+3 (center B)
            mkrow6(cp + 2 * SST, w3);    // row r0+4 (below B)

            const float4 oA = core3x3(w0, w1, w2, nax, nay, ncr2);
            const float4 oB = core3x3(w1, w2, w3, nax, nay, ncr2);

            if (TOG) {
                *(float4*)(gout + (r0    ) * W + 4 * q) = oA;
                *(float4*)(gout + (r0 + 1) * W + 4 * q) = oB;
            } else {
                *(float4*)(dst + (r0    ) * DSTST + 4 * q) = oA;
                *(float4*)(dst + (r0 + 1) * DSTST + 4 * q) = oB;
            }
        } else {
            // ---- generic 5x5 with per-tap uniform pruning (cold path) ----
            #pragma unroll
            for (int rr = 0; rr < 2; ++rr) {
                const float* cp2 = cp + rr * SST;
                const float4 M0 = *(const float4*)cp2;
                float cen[4] = {M0.x, M0.y, M0.z, M0.w};
                float num[4] = {M0.x, M0.y, M0.z, M0.w};
                float den[4] = {1.f, 1.f, 1.f, 1.f};
                #pragma unroll
                for (int dr = -2; dr <= 2; ++dr) {
                    const float ra = (float)(dr * dr) * nax;
                    const float rbest = dr ? ra : nay;
                    if (rbest < TH2) continue;
                    const float* rp2 = cp2 + dr * SST;
                    const float4 Lq = *(const float4*)(rp2 - 4);
                    const float4 Mq = *(const float4*)(rp2);
                    const float4 Rq = *(const float4*)(rp2 + 4);
                    const float w8[8] = {Lq.z, Lq.w, Mq.x, Mq.y, Mq.z, Mq.w,
                                         Rq.x, Rq.y};
                    #pragma unroll
                    for (int dc = -2; dc <= 2; ++dc) {
                        if (dr == 0 && dc == 0) continue;
                        const float b = ra + (float)(dc * dc) * nay;
                        if (b < TH2) continue;
                        #pragma unroll
                        for (int j = 0; j < 4; ++j) {
                            const float nb = w8[2 + j + dc];
                            const float d  = nb - cen[j];
                            const float tt = fmaf(d * d, ncr, b);
                            const float w  = EXP2(tt);
                            num[j] = fmaf(w, nb, num[j]);
                            den[j] += w;
                        }
                    }
                }
                float4 o;
                o.x = num[0] * RCP(den[0]);
                o.y = num[1] * RCP(den[1]);
                o.z = num[2] * RCP(den[2]);
                o.w = num[3] * RCP(den[3]);
                if (TOG) *(float4*)(gout + (r0 + rr) * W + 4 * q) = o;
                else     *(float4*)(dst + (r0 + rr) * DSTST + 4 * q) = o;
            }
        }
    }
}

__global__ __launch_bounds__(256)
void bilat3_fused(const float* __restrict__ in, float* __restrict__ out,
                  const float* __restrict__ sxyz, const float* __restrict__ srr,
                  int H, int W)
{
    __shared__ __align__(16) float buf0[S0R * S0C];   // 16192 B
    __shared__ __align__(16) float buf1[S1R * S1C];   // 13440 B -> 29.6 KB

    const int tid = threadIdx.x;
    const int X0 = blockIdx.x * TILE_X;
    const int Y0 = blockIdx.y * TILE_Y;
    const size_t img_off = (size_t)blockIdx.z * (size_t)H * (size_t)W;
    const float* __restrict__ img = in + img_off;

    // per-pass constants, -log2e pre-folded
    const float L2E = 1.4426950408889634f;
    float ncr[3], nax[3], nay[3];
    bool prune[3];
    #pragma unroll
    for (int p = 0; p < 3; ++p) {
        const float sx = sxyz[2 * p], sy = sxyz[2 * p + 1], sr = srr[p];
        ncr[p] = -0.5f / (sr * sr) * L2E;
        nax[p] = -0.5f / (sx * sx) * L2E;
        nay[p] = -0.5f / (sy * sy) * L2E;
        prune[p] = (4.f * nax[p] < TH2) && (4.f * nay[p] < TH2);
    }

    // ---- stage buf0: replicate-clamped input aperture ----
    {
        const int NQ0 = S0C / 4;  // 23 quads/row
        for (int t = tid; t < S0R * NQ0; t += 256) {
            const int r = t / NQ0, k = t - r * NQ0;
            const int gy = Y0 - 6 + r;
            const int gx = X0 - 12 + 4 * k;
            float4 v;
            if (gy >= 0 && gy < H && gx >= 0 && gx + 3 < W) {
                v = *(const float4*)(img + (size_t)gy * W + gx);  // aligned
            } else {
                const size_t rb = (size_t)min(max(gy, 0), H - 1) * W;
                v.x = img[rb + min(max(gx    , 0), W - 1)];
                v.y = img[rb + min(max(gx + 1, 0), W - 1)];
                v.z = img[rb + min(max(gx + 2, 0), W - 1)];
                v.w = img[rb + min(max(gx + 3, 0), W - 1)];
            }
            *(float4*)(buf0 + r * S0C + 4 * k) = v;
        }
    }
    __syncthreads();

    // ---- pass 1: buf0 -> buf1 (21 x 20 = 420 units) ----
    bilat_tile_pass<S1C / 4, S1R / 2, S0C, S1C, false>(
        buf0, buf1, nullptr, W, tid, ncr[0], nax[0], nay[0], prune[0]);
    __syncthreads();
    replicate_fill<S1R, S1C>(buf1,
        max(0, 4 - Y0), min(S1R - 1, (H - 1) - (Y0 - 4)),
        max(0, 8 - X0), min(S1C - 1, (W - 1) - (X0 - 8)), tid);
    __syncthreads();

    // ---- pass 2: buf1 -> buf2 (aliases buf0; staged input is dead) ----
    float* buf2 = buf0;
    bilat_tile_pass<S2C / 4, S2R / 2, S1C, S2C, false>(
        buf1, buf2, nullptr, W, tid, ncr[1], nax[1], nay[1], prune[1]);
    __syncthreads();
    replicate_fill<S2R, S2C>(buf2,
        max(0, 2 - Y0), min(S2R - 1, (H - 1) - (Y0 - 2)),
        max(0, 4 - X0), min(S2C - 1, (W - 1) - (X0 - 4)), tid);
    __syncthreads();

    // ---- pass 3: buf2 -> global (16 x 16 = 256 units, exactly 1 iter) ----
    float* gout = out + img_off + (size_t)Y0 * W + X0;
    bilat_tile_pass<TILE_X / 4, TILE_Y / 2, S2C, 0, true>(
        buf2, nullptr, gout, W, tid, ncr[2], nax[2], nay[2], prune[2]);
}

extern "C" void kernel_launch(void* const* d_in, const int* in_sizes, int n_in,
                              void* d_out, int out_size, void* d_ws, size_t ws_size,
                              hipStream_t stream)
{
    const float* x    = (const float*)d_in[0];
    const float* sxyz = (const float*)d_in[1];   // [3,2]
    const float* sr   = (const float*)d_in[2];   // [3]
    float* out = (float*)d_out;
    (void)d_ws; (void)ws_size;

    const int H = 512, W = 512;
    const int BC = in_sizes[0] / (H * W);        // 32

    dim3 block(256);
    dim3 grid(W / TILE_X, H / TILE_Y, BC);       // 8 x 16 x 32 = 4096 blocks

    bilat3_fused<<<grid, block, 0, stream>>>(x, out, sxyz, sr, H, W);
}

// Round 2
// 137.597 us; speedup vs baseline: 1.0482x; 1.0463x over previous
//
#include <hip/hip_runtime.h>

// Bilateral 5x5, 3 chained passes. [32,1,512,512] fp32, replicate padding,
// w = exp2(dr^2*nax + dc^2*nay + d^2*ncr).
//
// Round-10: DE-FUSED. Round-9 post-mortem: cutting LDS reads 33% changed
// nothing (conflicts -34%, dur flat) -> not LDS-bound. The real cost model:
// the fused-3 design computes 8144 px per 2048 useful px (3.98x overscan),
// and per-px cost is exp-dominated (8 v_exp_f32/px at quarter rate). VALU
// busy-time 50us == 3.98 x 12.6us/pass. Fusion saved ~20us of HBM and spent
// ~38us of redundant halo compute. So: 3 launches (in->out, out->ws,
// ws->out), each computing every pixel exactly once. Per-pass kernel:
// 10.7KB LDS aperture (8 blocks/CU wave cap), one barrier, exactly 256
// 2-row units per block (no loop, no tail), replicate handled by clamped
// staging against the full-image intermediate (exactly the reference's
// edge-padding semantics). Fused kernel retained as fallback if ws_size
// can't hold one [32,512,512] intermediate.
//
// Pruning (round 3): taps with spatial log2-weight < TH2 skipped via
// block-uniform branches -> effective 3x3 for sigma=0.5 (8 exps/px).
// Generic 5x5 path kept for large sigma.

typedef float v2f __attribute__((ext_vector_type(2)));

#define EXP2(x) __builtin_amdgcn_exp2f(x)
#define RCP(x)  __builtin_amdgcn_rcpf(x)
#define TH2 (-10.0f)

#define TILE_X 64
#define TILE_Y 32

// ---------------- shared tap core (validated rounds 8-9) ----------------

// Build 6-wide window row (cols c-1 .. c+4) from 3 aligned b128 quads.
__device__ __forceinline__ void mkrow6(const float* p, float* w6)
{
    const float4 L = *(const float4*)(p - 4);
    const float4 M = *(const float4*)(p);
    const float4 R = *(const float4*)(p + 4);
    w6[0] = L.w; w6[1] = M.x; w6[2] = M.y; w6[3] = M.z; w6[4] = M.w;
    w6[5] = R.x;
}

// One packed tap-pair: 5 pk ops + 2 exp for 2 pixels.
__device__ __forceinline__ void tap_pair(v2f nb, v2f ce, v2f& nu, v2f& de,
                                         float b, v2f ncr2)
{
    v2f d  = nb - ce;                                   // pk_add
    v2f tt = __builtin_elementwise_fma(d * d, ncr2,
                                       (v2f){b, b});    // pk_mul+pk_fma
    v2f w  = {EXP2(tt.x), EXP2(tt.y)};
    nu = __builtin_elementwise_fma(w, nb, nu);          // pk_fma
    de += w;                                            // pk_add
}

// All horizontal taps of one window row against centers c01/c23.
__device__ __forceinline__ void row_taps(const float* w6, v2f c01, v2f c23,
                                         v2f& n01, v2f& n23, v2f& d01, v2f& d23,
                                         float bm, float b0, float bp,
                                         bool skip0, v2f ncr2)
{
    tap_pair((v2f){w6[0], w6[1]}, c01, n01, d01, bm, ncr2);   // dc=-1
    tap_pair((v2f){w6[2], w6[3]}, c23, n23, d23, bm, ncr2);
    if (!skip0) {
        tap_pair((v2f){w6[1], w6[2]}, c01, n01, d01, b0, ncr2); // dc=0
        tap_pair((v2f){w6[3], w6[4]}, c23, n23, d23, b0, ncr2);
    }
    tap_pair((v2f){w6[2], w6[3]}, c01, n01, d01, bp, ncr2);   // dc=+1
    tap_pair((v2f){w6[4], w6[5]}, c23, n23, d23, bp, ncr2);
}

// Packed 3x3 bilateral core for 4 px: 16 tap-pairs = 80 pk ops + 32 exp.
__device__ __forceinline__ float4 core3x3(const float* wm, const float* wc,
                                          const float* wp,
                                          float nax, float nay, v2f ncr2)
{
    v2f c01 = {wc[1], wc[2]}, c23 = {wc[3], wc[4]};
    v2f n01 = c01, n23 = c23;               // center tap, w == 1
    v2f d01 = {1.f, 1.f}, d23 = {1.f, 1.f};
    const float bd = nax + nay;
    row_taps(wc, c01, c23, n01, n23, d01, d23, nay, 0.0f, nay, true,  ncr2);
    row_taps(wm, c01, c23, n01, n23, d01, d23, bd,  nax,  bd,  false, ncr2);
    row_taps(wp, c01, c23, n01, n23, d01, d23, bd,  nax,  bd,  false, ncr2);
    float4 o;
    o.x = n01.x * RCP(d01.x);
    o.y = n01.y * RCP(d01.y);
    o.z = n23.x * RCP(d23.x);
    o.w = n23.y * RCP(d23.y);
    return o;
}

// =======================================================================
// Round-10 primary path: one kernel per pass, no overscan compute.
// =======================================================================

#define PBR 36            // staged rows:  [Y0-2, Y0+33]
#define PBC 76            // staged cols:  [X0-4, X0+71], 304B stride (16B ok)

__global__ __launch_bounds__(256)
void bilat_pass(const float* __restrict__ in, float* __restrict__ out,
                const float* __restrict__ sxyz, const float* __restrict__ srr,
                int p, int H, int W)
{
    __shared__ __align__(16) float buf[PBR * PBC];   // 10944 B

    const int tid = threadIdx.x;
    const int X0 = blockIdx.x * TILE_X;
    const int Y0 = blockIdx.y * TILE_Y;
    const size_t img_off = (size_t)blockIdx.z * (size_t)H * (size_t)W;
    const float* __restrict__ img = in + img_off;

    const float L2E = 1.4426950408889634f;
    const float sx = sxyz[2 * p], sy = sxyz[2 * p + 1], sr = srr[p];
    const float ncr = -0.5f / (sr * sr) * L2E;
    const float nax = -0.5f / (sx * sx) * L2E;
    const float nay = -0.5f / (sy * sy) * L2E;
    const bool prune = (4.f * nax < TH2) && (4.f * nay < TH2);
    const v2f ncr2 = {ncr, ncr};

    // ---- stage: replicate-clamped aperture (36 x 19 quads = 684) ----
    {
        const int NQ = PBC / 4;   // 19
        for (int t = tid; t < PBR * NQ; t += 256) {
            const int r = t / NQ, k = t - r * NQ;
            const int gy = Y0 - 2 + r;
            const int gx = X0 - 4 + 4 * k;
            float4 v;
            if (gy >= 0 && gy < H && gx >= 0 && gx + 3 < W) {
                v = *(const float4*)(img + (size_t)gy * W + gx);  // aligned
            } else {
                const size_t rb = (size_t)min(max(gy, 0), H - 1) * W;
                v.x = img[rb + min(max(gx    , 0), W - 1)];
                v.y = img[rb + min(max(gx + 1, 0), W - 1)];
                v.z = img[rb + min(max(gx + 2, 0), W - 1)];
                v.w = img[rb + min(max(gx + 3, 0), W - 1)];
            }
            *(float4*)(buf + r * PBC + 4 * k) = v;
        }
    }
    __syncthreads();

    // ---- compute: exactly 256 2-row units (8 px each), no loop ----
    const int q  = tid & 15;          // quad 0..15
    const int rp = tid >> 4;          // row-pair 0..15
    const int r0 = 2 * rp;
    const float* cp = buf + (r0 + 2) * PBC + 4 * q + 4;   // center row A
    float* gout = out + img_off + (size_t)(Y0 + r0) * W + (X0 + 4 * q);

    if (prune) {
        float w0[6], w1[6], w2[6], w3[6];
        mkrow6(cp - PBC,     w0);    // above A
        mkrow6(cp,           w1);    // center A
        mkrow6(cp + PBC,     w2);    // center B
        mkrow6(cp + 2 * PBC, w3);    // below B

        const float4 oA = core3x3(w0, w1, w2, nax, nay, ncr2);
        const float4 oB = core3x3(w1, w2, w3, nax, nay, ncr2);
        *(float4*)(gout)     = oA;
        *(float4*)(gout + W) = oB;
    } else {
        // ---- generic 5x5 with per-tap uniform pruning (cold path) ----
        #pragma unroll
        for (int rr = 0; rr < 2; ++rr) {
            const float* cp2 = cp + rr * PBC;
            const float4 M0 = *(const float4*)cp2;
            float cen[4] = {M0.x, M0.y, M0.z, M0.w};
            float num[4] = {M0.x, M0.y, M0.z, M0.w};
            float den[4] = {1.f, 1.f, 1.f, 1.f};
            #pragma unroll
            for (int dr = -2; dr <= 2; ++dr) {
                const float ra = (float)(dr * dr) * nax;
                const float rbest = dr ? ra : nay;
                if (rbest < TH2) continue;
                const float* rp2 = cp2 + dr * PBC;
                const float4 Lq = *(const float4*)(rp2 - 4);
                const float4 Mq = *(const float4*)(rp2);
                const float4 Rq = *(const float4*)(rp2 + 4);
                const float w8[8] = {Lq.z, Lq.w, Mq.x, Mq.y, Mq.z, Mq.w,
                                     Rq.x, Rq.y};
                #pragma unroll
                for (int dc = -2; dc <= 2; ++dc) {
                    if (dr == 0 && dc == 0) continue;
                    const float b = ra + (float)(dc * dc) * nay;
                    if (b < TH2) continue;
                    #pragma unroll
                    for (int j = 0; j < 4; ++j) {
                        const float nb = w8[2 + j + dc];
                        const float d  = nb - cen[j];
                        const float tt = fmaf(d * d, ncr, b);
                        const float w  = EXP2(tt);
                        num[j] = fmaf(w, nb, num[j]);
                        den[j] += w;
                    }
                }
            }
            float4 o;
            o.x = num[0] * RCP(den[0]);
            o.y = num[1] * RCP(den[1]);
            o.z = num[2] * RCP(den[2]);
            o.w = num[3] * RCP(den[3]);
            *(float4*)(gout + rr * W) = o;
        }
    }
}

// =======================================================================
// Fallback: fused 3-pass kernel (round-9 code) if workspace is too small.
// =======================================================================

#define S0R 44
#define S0C 92
#define S1R 40
#define S1C 84
#define S2R 36
#define S2C 76

template<int NR, int NC>
__device__ __forceinline__ void replicate_fill(float* buf, int rlo, int rhi,
                                               int vlo, int vhi, int tid)
{
    if (rlo == 0 && vlo == 0 && rhi == NR - 1 && vhi == NC - 1) return;
    for (int t = tid; t < NR * NC; t += 256) {
        const int r = t / NC, v = t - r * NC;
        const int rs = min(max(r, rlo), rhi);
        const int vs = min(max(v, vlo), vhi);
        if (rs != r || vs != v) buf[r * NC + v] = buf[rs * NC + vs];
    }
}

template<int NQ, int NRH, int SST, int DSTST, bool TOG>
__device__ __forceinline__ void bilat_tile_pass(
    const float* __restrict__ src, float* __restrict__ dst,
    float* __restrict__ gout, int W,
    int tid, float ncr, float nax, float nay, bool prune)
{
    const v2f ncr2 = {ncr, ncr};
    for (int t = tid; t < NQ * NRH; t += 256) {
        const int rp = t / NQ;
        const int q  = t - rp * NQ;
        const int r0 = 2 * rp;
        const float* cp = src + (r0 + 2) * SST + 4 * q + 4;

        if (prune) {
            float w0[6], w1[6], w2[6], w3[6];
            mkrow6(cp - SST,     w0);
            mkrow6(cp,           w1);
            mkrow6(cp + SST,     w2);
            mkrow6(cp + 2 * SST, w3);
            const float4 oA = core3x3(w0, w1, w2, nax, nay, ncr2);
            const float4 oB = core3x3(w1, w2, w3, nax, nay, ncr2);
            if (TOG) {
                *(float4*)(gout + (r0    ) * W + 4 * q) = oA;
                *(float4*)(gout + (r0 + 1) * W + 4 * q) = oB;
            } else {
                *(float4*)(dst + (r0    ) * DSTST + 4 * q) = oA;
                *(float4*)(dst + (r0 + 1) * DSTST + 4 * q) = oB;
            }
        } else {
            #pragma unroll
            for (int rr = 0; rr < 2; ++rr) {
                const float* cp2 = cp + rr * SST;
                const float4 M0 = *(const float4*)cp2;
                float cen[4] = {M0.x, M0.y, M0.z, M0.w};
                float num[4] = {M0.x, M0.y, M0.z, M0.w};
                float den[4] = {1.f, 1.f, 1.f, 1.f};
                #pragma unroll
                for (int dr = -2; dr <= 2; ++dr) {
                    const float ra = (float)(dr * dr) * nax;
                    const float rbest = dr ? ra : nay;
                    if (rbest < TH2) continue;
                    const float* rp2 = cp2 + dr * SST;
                    const float4 Lq = *(const float4*)(rp2 - 4);
                    const float4 Mq = *(const float4*)(rp2);
                    const float4 Rq = *(const float4*)(rp2 + 4);
                    const float w8[8] = {Lq.z, Lq.w, Mq.x, Mq.y, Mq.z, Mq.w,
                                         Rq.x, Rq.y};
                    #pragma unroll
                    for (int dc = -2; dc <= 2; ++dc) {
                        if (dr == 0 && dc == 0) continue;
                        const float b = ra + (float)(dc * dc) * nay;
                        if (b < TH2) continue;
                        #pragma unroll
                        for (int j = 0; j < 4; ++j) {
                            const float nb = w8[2 + j + dc];
                            const float d  = nb - cen[j];
                            const float tt = fmaf(d * d, ncr, b);
                            const float w  = EXP2(tt);
                            num[j] = fmaf(w, nb, num[j]);
                            den[j] += w;
                        }
                    }
                }
                float4 o;
                o.x = num[0] * RCP(den[0]);
                o.y = num[1] * RCP(den[1]);
                o.z = num[2] * RCP(den[2]);
                o.w = num[3] * RCP(den[3]);
                if (TOG) *(float4*)(gout + (r0 + rr) * W + 4 * q) = o;
                else     *(float4*)(dst + (r0 + rr) * DSTST + 4 * q) = o;
            }
        }
    }
}

__global__ __launch_bounds__(256)
void bilat3_fused(const float* __restrict__ in, float* __restrict__ out,
                  const float* __restrict__ sxyz, const float* __restrict__ srr,
                  int H, int W)
{
    __shared__ __align__(16) float buf0[S0R * S0C];
    __shared__ __align__(16) float buf1[S1R * S1C];

    const int tid = threadIdx.x;
    const int X0 = blockIdx.x * TILE_X;
    const int Y0 = blockIdx.y * TILE_Y;
    const size_t img_off = (size_t)blockIdx.z * (size_t)H * (size_t)W;
    const float* __restrict__ img = in + img_off;

    const float L2E = 1.4426950408889634f;
    float ncr[3], nax[3], nay[3];
    bool prune[3];
    #pragma unroll
    for (int p = 0; p < 3; ++p) {
        const float sx = sxyz[2 * p], sy = sxyz[2 * p + 1], sr = srr[p];
        ncr[p] = -0.5f / (sr * sr) * L2E;
        nax[p] = -0.5f / (sx * sx) * L2E;
        nay[p] = -0.5f / (sy * sy) * L2E;
        prune[p] = (4.f * nax[p] < TH2) && (4.f * nay[p] < TH2);
    }

    {
        const int NQ0 = S0C / 4;
        for (int t = tid; t < S0R * NQ0; t += 256) {
            const int r = t / NQ0, k = t - r * NQ0;
            const int gy = Y0 - 6 + r;
            const int gx = X0 - 12 + 4 * k;
            float4 v;
            if (gy >= 0 && gy < H && gx >= 0 && gx + 3 < W) {
                v = *(const float4*)(img + (size_t)gy * W + gx);
            } else {
                const size_t rb = (size_t)min(max(gy, 0), H - 1) * W;
                v.x = img[rb + min(max(gx    , 0), W - 1)];
                v.y = img[rb + min(max(gx + 1, 0), W - 1)];
                v.z = img[rb + min(max(gx + 2, 0), W - 1)];
                v.w = img[rb + min(max(gx + 3, 0), W - 1)];
            }
            *(float4*)(buf0 + r * S0C + 4 * k) = v;
        }
    }
    __syncthreads();

    bilat_tile_pass<S1C / 4, S1R / 2, S0C, S1C, false>(
        buf0, buf1, nullptr, W, tid, ncr[0], nax[0], nay[0], prune[0]);
    __syncthreads();
    replicate_fill<S1R, S1C>(buf1,
        max(0, 4 - Y0), min(S1R - 1, (H - 1) - (Y0 - 4)),
        max(0, 8 - X0), min(S1C - 1, (W - 1) - (X0 - 8)), tid);
    __syncthreads();

    float* buf2 = buf0;
    bilat_tile_pass<S2C / 4, S2R / 2, S1C, S2C, false>(
        buf1, buf2, nullptr, W, tid, ncr[1], nax[1], nay[1], prune[1]);
    __syncthreads();
    replicate_fill<S2R, S2C>(buf2,
        max(0, 2 - Y0), min(S2R - 1, (H - 1) - (Y0 - 2)),
        max(0, 4 - X0), min(S2C - 1, (W - 1) - (X0 - 4)), tid);
    __syncthreads();

    float* gout = out + img_off + (size_t)Y0 * W + X0;
    bilat_tile_pass<TILE_X / 4, TILE_Y / 2, S2C, 0, true>(
        buf2, nullptr, gout, W, tid, ncr[2], nax[2], nay[2], prune[2]);
}

// =======================================================================

extern "C" void kernel_launch(void* const* d_in, const int* in_sizes, int n_in,
                              void* d_out, int out_size, void* d_ws, size_t ws_size,
                              hipStream_t stream)
{
    const float* x    = (const float*)d_in[0];
    const float* sxyz = (const float*)d_in[1];   // [3,2]
    const float* sr   = (const float*)d_in[2];   // [3]
    float* out = (float*)d_out;

    const int H = 512, W = 512;
    const int BC = in_sizes[0] / (H * W);        // 32

    dim3 block(256);
    dim3 grid(W / TILE_X, H / TILE_Y, BC);       // 8 x 16 x 32 = 4096 blocks

    const size_t need = (size_t)BC * H * W * sizeof(float);
    if (d_ws && ws_size >= need) {
        float* ws = (float*)d_ws;
        // pass 1: in -> out, pass 2: out -> ws, pass 3: ws -> out
        bilat_pass<<<grid, block, 0, stream>>>(x,   out, sxyz, sr, 0, H, W);
        bilat_pass<<<grid, block, 0, stream>>>(out, ws,  sxyz, sr, 1, H, W);
        bilat_pass<<<grid, block, 0, stream>>>(ws,  out, sxyz, sr, 2, H, W);
    } else {
        bilat3_fused<<<grid, block, 0, stream>>>(x, out, sxyz, sr, H, W);
    }
}